// Round 5
// baseline (231.974 us; speedup 1.0000x reference)
//
#include <hip/hip_runtime.h>

// ROI Align (crop_and_resize-style bilinear), fp32.
// fmaps: [8,128,128,256], rois: [8,128,4] (x1,y1,x2,y2), out: [8,128,7,7,256]
//
// CALIBRATION ROUND: identical row-per-wave kernel launched TWICE per call
// (second launch overwrites d_out with identical values). dur_us delta vs the
// single-launch 200.7us measures the kernel's true steady-state time K, which
// is otherwise invisible (harness poison/restore ops dominate the graph and
// the top-5 rocprof rows).
//
// One wave = one ROI output ROW (7 pixels); lane = one float4 of channels.

#define NBATCH 8
#define NROI   128
#define FH     128
#define FW     128
#define NC     256
#define OH     7
#define OW     7

typedef float f32x4 __attribute__((ext_vector_type(4)));

template<int N>
__device__ __forceinline__ void do_chunk(
    int j0, float in_x0, float dxw, bool vy, float ly,
    const f32x4* __restrict__ r0, const f32x4* __restrict__ r1,
    int lane, f32x4* __restrict__ ob)
{
    f32x4 tl[N], tr[N], bl[N], br[N];
    float lx[N], m[N];

#pragma unroll
    for (int k = 0; k < N; ++k) {
        const int j = j0 + k;
        // reference op order: bx1*(Wf-1) + j * ((bx2-bx1)*(Wf-1)/6)
        float in_x = in_x0 + (float)j * dxw;
        const bool vx = (in_x >= 0.0f) & (in_x <= 127.0f);
        in_x = fminf(fmaxf(in_x, 0.0f), 127.0f);
        const float x0f = floorf(in_x);
        lx[k] = in_x - x0f;
        const int x0  = (int)x0f;
        const int x1i = min(x0 + 1, FW - 1);
        tl[k] = r0[x0  * 64 + lane];
        tr[k] = r0[x1i * 64 + lane];
        bl[k] = r1[x0  * 64 + lane];
        br[k] = r1[x1i * 64 + lane];
        m[k] = (vy & vx) ? 1.0f : 0.0f;
    }

#pragma unroll
    for (int k = 0; k < N; ++k) {
        const f32x4 top = tl[k] + (tr[k] - tl[k]) * lx[k];
        const f32x4 bot = bl[k] + (br[k] - bl[k]) * lx[k];
        const f32x4 o   = (top + (bot - top) * ly) * m[k];
        __builtin_nontemporal_store(o, ob + (size_t)(j0 + k) * 64 + lane);
    }
}

__global__ __launch_bounds__(256) void roi_align_kernel(
    const float* __restrict__ fmaps,
    const float* __restrict__ rois,
    float* __restrict__ out)
{
    const int lane = threadIdx.x & 63;
    // wave-uniform row id: (b, roi, i) flattened. 4 waves per block.
    const int row = __builtin_amdgcn_readfirstlane(
        (int)blockIdx.x * 4 + ((int)threadIdx.x >> 6));

    const int i   = row % OH;
    int t         = row / OH;
    const int roi = t % NROI;
    const int b   = t / NROI;

    // wave-uniform ROI load -> s_load_dwordx4
    const float* r = rois + (size_t)(b * NROI + roi) * 4;
    const float x1 = r[0], y1 = r[1], x2 = r[2], y2 = r[3];

    const float Hf = 128.0f, Wf = 128.0f;
    // Replicate reference op order exactly: (v * Hf) / (Hf - 1)
    const float by1 = y1 * Hf / (Hf - 1.0f);
    const float bx1 = x1 * Wf / (Wf - 1.0f);
    const float by2 = y2 * Hf / (Hf - 1.0f);
    const float bx2 = x2 * Wf / (Wf - 1.0f);

    float in_y = by1 * (Hf - 1.0f) + (float)i * ((by2 - by1) * (Hf - 1.0f) / 6.0f);
    const bool vy = (in_y >= 0.0f) & (in_y <= Hf - 1.0f);
    in_y = fminf(fmaxf(in_y, 0.0f), Hf - 1.0f);

    const float y0f = floorf(in_y);
    const float ly  = in_y - y0f;
    const int   y0  = (int)y0f;
    const int   y1i = min(y0 + 1, FH - 1);

    // x interpolation params (shared by all 7 pixels of this row)
    const float in_x0 = bx1 * (Wf - 1.0f);
    const float dxw   = (bx2 - bx1) * (Wf - 1.0f) / 6.0f;

    // fmap row bases for this wave (f32x4 units: (y*FW + x)*64 + lane)
    const f32x4* __restrict__ f =
        (const f32x4*)(fmaps + (size_t)b * FH * FW * NC);
    const f32x4* __restrict__ r0 = f + (size_t)y0  * FW * 64;
    const f32x4* __restrict__ r1 = f + (size_t)y1i * FW * 64;

    // output base for this row: 7 contiguous pixels x 1KB
    f32x4* __restrict__ ob = (f32x4*)out + (size_t)row * OW * 64;

    do_chunk<4>(0, in_x0, dxw, vy, ly, r0, r1, lane, ob);
    do_chunk<3>(4, in_x0, dxw, vy, ly, r0, r1, lane, ob);
}

extern "C" void kernel_launch(void* const* d_in, const int* in_sizes, int n_in,
                              void* d_out, int out_size, void* d_ws, size_t ws_size,
                              hipStream_t stream) {
    const float* fmaps = (const float*)d_in[0];
    const float* rois  = (const float*)d_in[1];
    float* out = (float*)d_out;

    // 8*128*7 = 7168 rows, one wave each, 4 waves/block -> 1792 blocks
    const int rows = NBATCH * NROI * OH;
    // CALIBRATION: launch twice; dur_us delta vs single launch == kernel time.
    roi_align_kernel<<<rows / 4, 256, 0, stream>>>(fmaps, rois, out);
    roi_align_kernel<<<rows / 4, 256, 0, stream>>>(fmaps, rois, out);
}

// Round 6
// 199.423 us; speedup vs baseline: 1.1632x; 1.1632x over previous
//
#include <hip/hip_runtime.h>

// ROI Align (crop_and_resize-style bilinear), fp32.
// fmaps: [8,128,128,256], rois: [8,128,4] (x1,y1,x2,y2), out: [8,128,7,7,256]
//
// FINAL (single launch, calibration removed). Round-5 calibration measured
// kernel steady-state time K ~= 31.2us (double-launch 232.0 vs single 200.7).
// Floor arithmetic: 51 MB HBM write ~= 8us + ~205 MB L3-resident corner reads;
// effective 8.3 TB/s > HBM-achievable 6.3 TB/s => cache-roofline-bound.
// Rounds 1-4 (three structurally different kernels, all ~200us) confirm the
// remaining dur_us is fixed harness graph overhead (~170us of poison/restore).
//
// One wave = one ROI output ROW (7 pixels); lane = one float4 of channels.
// ROI math + y-row pair computed once per wave; 28 corner gathers issued in
// bulk (high MLP), monotone in x along two fmap rows; contiguous 7KB
// nontemporal output stream per wave.

#define NBATCH 8
#define NROI   128
#define FH     128
#define FW     128
#define NC     256
#define OH     7
#define OW     7

typedef float f32x4 __attribute__((ext_vector_type(4)));

template<int N>
__device__ __forceinline__ void do_chunk(
    int j0, float in_x0, float dxw, bool vy, float ly,
    const f32x4* __restrict__ r0, const f32x4* __restrict__ r1,
    int lane, f32x4* __restrict__ ob)
{
    f32x4 tl[N], tr[N], bl[N], br[N];
    float lx[N], m[N];

#pragma unroll
    for (int k = 0; k < N; ++k) {
        const int j = j0 + k;
        // reference op order: bx1*(Wf-1) + j * ((bx2-bx1)*(Wf-1)/6)
        float in_x = in_x0 + (float)j * dxw;
        const bool vx = (in_x >= 0.0f) & (in_x <= 127.0f);
        in_x = fminf(fmaxf(in_x, 0.0f), 127.0f);
        const float x0f = floorf(in_x);
        lx[k] = in_x - x0f;
        const int x0  = (int)x0f;
        const int x1i = min(x0 + 1, FW - 1);
        tl[k] = r0[x0  * 64 + lane];
        tr[k] = r0[x1i * 64 + lane];
        bl[k] = r1[x0  * 64 + lane];
        br[k] = r1[x1i * 64 + lane];
        m[k] = (vy & vx) ? 1.0f : 0.0f;
    }

#pragma unroll
    for (int k = 0; k < N; ++k) {
        const f32x4 top = tl[k] + (tr[k] - tl[k]) * lx[k];
        const f32x4 bot = bl[k] + (br[k] - bl[k]) * lx[k];
        const f32x4 o   = (top + (bot - top) * ly) * m[k];
        __builtin_nontemporal_store(o, ob + (size_t)(j0 + k) * 64 + lane);
    }
}

__global__ __launch_bounds__(256) void roi_align_kernel(
    const float* __restrict__ fmaps,
    const float* __restrict__ rois,
    float* __restrict__ out)
{
    const int lane = threadIdx.x & 63;
    // wave-uniform row id: (b, roi, i) flattened. 4 waves per block.
    const int row = __builtin_amdgcn_readfirstlane(
        (int)blockIdx.x * 4 + ((int)threadIdx.x >> 6));

    const int i   = row % OH;
    int t         = row / OH;
    const int roi = t % NROI;
    const int b   = t / NROI;

    // wave-uniform ROI load -> s_load_dwordx4
    const float* r = rois + (size_t)(b * NROI + roi) * 4;
    const float x1 = r[0], y1 = r[1], x2 = r[2], y2 = r[3];

    const float Hf = 128.0f, Wf = 128.0f;
    // Replicate reference op order exactly: (v * Hf) / (Hf - 1)
    const float by1 = y1 * Hf / (Hf - 1.0f);
    const float bx1 = x1 * Wf / (Wf - 1.0f);
    const float by2 = y2 * Hf / (Hf - 1.0f);
    const float bx2 = x2 * Wf / (Wf - 1.0f);

    float in_y = by1 * (Hf - 1.0f) + (float)i * ((by2 - by1) * (Hf - 1.0f) / 6.0f);
    const bool vy = (in_y >= 0.0f) & (in_y <= Hf - 1.0f);
    in_y = fminf(fmaxf(in_y, 0.0f), Hf - 1.0f);

    const float y0f = floorf(in_y);
    const float ly  = in_y - y0f;
    const int   y0  = (int)y0f;
    const int   y1i = min(y0 + 1, FH - 1);

    // x interpolation params (shared by all 7 pixels of this row)
    const float in_x0 = bx1 * (Wf - 1.0f);
    const float dxw   = (bx2 - bx1) * (Wf - 1.0f) / 6.0f;

    // fmap row bases for this wave (f32x4 units: (y*FW + x)*64 + lane)
    const f32x4* __restrict__ f =
        (const f32x4*)(fmaps + (size_t)b * FH * FW * NC);
    const f32x4* __restrict__ r0 = f + (size_t)y0  * FW * 64;
    const f32x4* __restrict__ r1 = f + (size_t)y1i * FW * 64;

    // output base for this row: 7 contiguous pixels x 1KB
    f32x4* __restrict__ ob = (f32x4*)out + (size_t)row * OW * 64;

    do_chunk<4>(0, in_x0, dxw, vy, ly, r0, r1, lane, ob);
    do_chunk<3>(4, in_x0, dxw, vy, ly, r0, r1, lane, ob);
}

extern "C" void kernel_launch(void* const* d_in, const int* in_sizes, int n_in,
                              void* d_out, int out_size, void* d_ws, size_t ws_size,
                              hipStream_t stream) {
    const float* fmaps = (const float*)d_in[0];
    const float* rois  = (const float*)d_in[1];
    float* out = (float*)d_out;

    // 8*128*7 = 7168 rows, one wave each, 4 waves/block -> 1792 blocks
    const int rows = NBATCH * NROI * OH;
    roi_align_kernel<<<rows / 4, 256, 0, stream>>>(fmaps, rois, out);
}